// Round 10
// baseline (900.193 us; speedup 1.0000x reference)
//
#include <hip/hip_runtime.h>

// LstmSequential round 10: 4 blocks/CU (1024 blocks x 4 rows) — fill barrier waits
// with independent blocks. r9's coop experiment proved the ~80us total-vs-kernel gap
// is harness-fixed (persists with a single kernel), so all effort goes to the
// recurrence kernel: r8 was latency/rendezvous-bound at 2 waves/SIMD (removing
// instructions was neutral), so quadruple the independent-wave count per SIMD.
//  - rows at tile-row 4q only (reg 0); regs/rows 4q+1..3 dead (zero in LDS, garbage
//    in acc, never read). Per-wave epilogue halves vs r8; weights VGPRs unchanged.
//  - __launch_bounds__(256,4): VGPR cap 128 (audit ~100, no spill expected).
//  - everything else identical to r8: split prep kernel, 1 lgkm-only barrier/step,
//    register-cached h1 frags, depth-2 f32 E1 gather folded into acc init, exp2 acts.
// Fallback to round-1 monolithic kernel if ws too small.

#define VOCAB 10000
#define EMB   100
#define SEQ   80
#define BATCH 4096
#define NGRID 1024                   // 4 rows/block

typedef _Float16 f16;
typedef _Float16 f16x8 __attribute__((ext_vector_type(8)));
typedef _Float16 half2_t __attribute__((ext_vector_type(2)));
typedef float    f32x4 __attribute__((ext_vector_type(4)));
typedef unsigned int uint;

#define LOG2E 1.4426950408889634f

__device__ __forceinline__ uint pack2(float lo, float hi) {
    return __builtin_bit_cast(uint, __builtin_amdgcn_cvt_pkrtz(lo, hi));
}
__device__ __forceinline__ uint rl_u(uint v, int l) { return (uint)__builtin_amdgcn_readlane((int)v, l); }
__device__ __forceinline__ float dot2(uint a, uint b, float c) {
    return __builtin_amdgcn_fdot2(__builtin_bit_cast(half2_t, a), __builtin_bit_cast(half2_t, b), c, false);
}
__device__ __forceinline__ f32x4 mfma16(uint4 a, uint4 b, f32x4 c) {
    return __builtin_amdgcn_mfma_f32_16x16x32_f16(
        __builtin_bit_cast(f16x8, a), __builtin_bit_cast(f16x8, b), c, 0, 0, 0);
}
// Barrier draining ONLY LDS ops — global gathers stay outstanding.
__device__ __forceinline__ void barrier_lds() {
    asm volatile("s_waitcnt lgkmcnt(0)\n\ts_barrier" ::: "memory");
}
__device__ __forceinline__ float sigm_e(float x) {
    float t = __builtin_amdgcn_exp2f(-LOG2E * x);
    return __builtin_amdgcn_rcpf(1.0f + t);
}
__device__ __forceinline__ float tanh_e(float x) {
    float t = __builtin_amdgcn_exp2f((2.0f * LOG2E) * x);
    return __builtin_fmaf(-2.0f, __builtin_amdgcn_rcpf(1.0f + t), 1.0f);
}
__device__ __forceinline__ float sigm_exact(float x) {
    return 1.0f / (1.0f + __expf(-x));
}

// ---------------- workspace layout (bytes) ----------------
#define WS_E1F_OFF 0                 // VOCAB*256 f32  = 10,240,000
#define WS_B1F_OFF 10240000          // 2048 uint4     = 32,768
#define WS_B2F_OFF 10272768          // 4096 uint4     = 65,536
#define WS_NEEDED  10338304

// ---------------- prep_e1: E1 table + B-fragment packing (split, r8) ----------------
#define NB_E1 512
__global__ __launch_bounds__(256) void prep_e1(
    const float* __restrict__ emb,
    const float* __restrict__ W1, const float* __restrict__ U1,
    const float* __restrict__ b1,
    const float* __restrict__ W2, const float* __restrict__ U2,
    float* __restrict__ E1f, uint* __restrict__ B1f, uint* __restrict__ B2f) {
    if (blockIdx.x < NB_E1) {
        // role A: thread c owns raw col c (coalesced W1 loads); store applies the
        // [v][u][g] permutation: E1f[v*256 + u*4 + g].
        const int c    = threadIdx.x;
        const int lane = c & 63;
        uint w[50];
#pragma unroll
        for (int kp = 0; kp < 50; ++kp)
            w[kp] = pack2(W1[(2 * kp) * 256 + c], W1[(2 * kp + 1) * 256 + c]);
        const float bias = b1[c];
        const int   dst  = (c & 63) * 4 + (c >> 6);
        float2 ecur = {0.f, 0.f};
        if (lane < 50) ecur = *(const float2*)(emb + (size_t)blockIdx.x * EMB + 2 * lane);
        for (int v = blockIdx.x; v < VOCAB; v += NB_E1) {
            float2 enext = {0.f, 0.f};
            if (v + NB_E1 < VOCAB && lane < 50)
                enext = *(const float2*)(emb + (size_t)(v + NB_E1) * EMB + 2 * lane);
            uint ep = pack2(ecur.x, ecur.y);
            float a0 = bias, a1 = 0.0f;
#pragma unroll
            for (int kp = 0; kp < 50; kp += 2) {
                a0 = dot2(w[kp],     rl_u(ep, kp),     a0);
                a1 = dot2(w[kp + 1], rl_u(ep, kp + 1), a1);
            }
            E1f[v * 256 + dst] = a0 + a1;
            ecur = enext;
        }
    } else {
        // role B: B-fragment packing (16x16x32 f16 layout: lane holds
        // B[k = kt*32 + (lane>>4)*8 + j][n = lane&15], dword dw: j=2dw lo, 2dw+1 hi)
        int idx = (blockIdx.x - NB_E1) * 256 + threadIdx.x;   // 0..16383
        if (idx < 8192) {                                     // B1f (U1, 64x256)
            int dw = idx & 3, lane = (idx >> 2) & 63, kt = (idx >> 8) & 1,
                g = (idx >> 9) & 3, w = idx >> 11;
            int k   = kt * 32 + (lane >> 4) * 8 + dw * 2;
            int col = g * 64 + w * 16 + (lane & 15);
            B1f[idx] = pack2(U1[k * 256 + col], U1[(k + 1) * 256 + col]);
        }
        if (idx < 16384) {                                    // B2f ([W2;U2], 128x256)
            int dw = idx & 3, lane = (idx >> 2) & 63, kt = (idx >> 8) & 3,
                g = (idx >> 10) & 3, w = idx >> 12;
            int k   = kt * 32 + (lane >> 4) * 8 + dw * 2;
            int col = g * 64 + w * 16 + (lane & 15);
            float lo = (k < 64) ? W2[k * 256 + col] : U2[(k - 64) * 256 + col];
            float hi = (k < 63) ? W2[(k + 1) * 256 + col] : U2[(k + 1 - 64) * 256 + col];
            B2f[idx] = pack2(lo, hi);
        }
    }
}

// ---------------- fused 2-layer LSTM + head, 4 rows/block, 4 blocks/CU ----------------
// A-buffer (ping-pong buf b): fp16 A-matrix [16 m x 128 k] in fragment layout,
//   f16 index of (m,k) = ((k>>3)*16 + m)*8 + (k&7); lane's kt-frag = uint4 [kt*64+lane].
//   k 0..63 = h1, k 64..127 = h2. Batch row (row0+q) at tile-row 4q; rows 4q+1..3
//   stay zero forever (acc regs 1..3 garbage, never read).
// Step t (p = t&1): MFMA1 uses register-cached h1(t-1) frags | epi1 writes
//   buf[1-p].h1 | gather e1(t+2) | BARRIER | MFMA2 ds_reads buf[1-p].h1 (cached for
//   next step) + buf[p].h2 | epi2 writes buf[1-p].h2.
__global__ __launch_bounds__(256, 4) void lstm_mfma(
    const int* __restrict__ tokens, const f32x4* __restrict__ E1f4,
    const uint4* __restrict__ B1f, const uint4* __restrict__ B2f,
    const float* __restrict__ b2, const float* __restrict__ Wd,
    const float* __restrict__ bd, float* __restrict__ out) {
    __shared__ uint4 AbufU[512];                  // 2 bufs x 256 uint4 = 8 KB
    __shared__ float red[16];
    f16* Abuf = (f16*)AbufU;

    const int tid  = threadIdx.x;
    const int w    = tid >> 6;
    const int lane = tid & 63;
    const int q    = lane >> 4;
    const int li   = lane & 15;
    const int u    = w * 16 + li;                 // this lane's unit (output col)
    const int row0 = blockIdx.x * 4;
    const int row  = row0 + q;                    // this lane's batch row (tile-row 4q)

    const uint4 z4 = {0u, 0u, 0u, 0u};
    AbufU[tid] = z4; AbufU[tid + 256] = z4;       // zero both buffers

    // persistent B fragments (96 VGPRs)
    uint4 b1f[4][2], b2f[4][4];
#pragma unroll
    for (int g = 0; g < 4; ++g) {
#pragma unroll
        for (int kt = 0; kt < 2; ++kt) b1f[g][kt] = B1f[((w * 4 + g) * 2 + kt) * 64 + lane];
#pragma unroll
        for (int kt = 0; kt < 4; ++kt) b2f[g][kt] = B2f[((w * 4 + g) * 4 + kt) * 64 + lane];
    }
    float b2v[4];
#pragma unroll
    for (int g = 0; g < 4; ++g) b2v[g] = b2[g * 64 + u];
    const float wdv = Wd[u];
    const float bdv = bd[0];

    // token window + depth-2 E1 prefetch (1 row/lane)
    int4  tokc, tokn;
    f32x4 e1buf[2];
    tokc = *(const int4*)(tokens + (size_t)row * SEQ);
    e1buf[0] = E1f4[(size_t)tokc.x * 64 + u];
    e1buf[1] = E1f4[(size_t)tokc.y * 64 + u];

    float c1 = 0.f, c2 = 0.f, h2v = 0.f;
    uint4 a0c = z4, a1c = z4;                     // cached h1(t-1) A-frags

    __syncthreads();                              // init barrier (full drain, once)

#pragma unroll 1
    for (int t4 = 0; t4 < SEQ / 4; ++t4) {
        if (t4 < SEQ / 4 - 1)
            tokn = *(const int4*)(tokens + (size_t)row * SEQ + (t4 + 1) * 4);
#pragma unroll
        for (int s = 0; s < 4; ++s) {
            const int p = s & 1;                  // == t&1
            // ---- layer 1 MFMA: z1 = e1 (in C) + h1_{t-1} @ U1 — pure registers ----
            f32x4 acc[4];
#pragma unroll
            for (int g = 0; g < 4; ++g)           // regs 1..3 undefined (dead rows)
                acc[g][0] = e1buf[p][g];
#pragma unroll
            for (int g = 0; g < 4; ++g) acc[g] = mfma16(a0c, b1f[g][0], acc[g]);
#pragma unroll
            for (int g = 0; g < 4; ++g) acc[g] = mfma16(a1c, b1f[g][1], acc[g]);

            // ---- epilogue 1 (1 row), writes h1_t -> buf[1-p] ----
            {
                float ig = sigm_e(acc[0][0]);
                float fg = sigm_e(acc[1][0]);
                float gv = tanh_e(acc[2][0]);
                float og = sigm_e(acc[3][0]);
                c1 = fg * c1 + ig * gv;
                float h1 = og * tanh_e(c1);
                Abuf[(1 - p) * 2048 + ((u >> 3) * 16 + 4 * q) * 8 + (u & 7)] = (f16)h1;
            }

            // gather e1 for t+2 (registers only — pre-barrier, max in-flight)
            if (t4 * 4 + s + 2 < SEQ) {
                int tk = (s == 0) ? tokc.z : (s == 1) ? tokc.w
                       : (s == 2) ? tokn.x : tokn.y;
                e1buf[p] = E1f4[(size_t)tk * 64 + u];
            }

            barrier_lds();                        // lgkm-only: gathers stay in flight

            // ---- layer 2 MFMA: z2 = b2 (in C) + [h1_t | h2_{t-1}] @ [W2;U2] ----
            uint4 a[4];
            a[0] = AbufU[(1 - p) * 256 + lane];   // h1(t) — cached for next MFMA1
            a[1] = AbufU[(1 - p) * 256 + 64 + lane];
            a[2] = AbufU[p * 256 + 128 + lane];   // h2(t-1)
            a[3] = AbufU[p * 256 + 192 + lane];
            f32x4 acc2[4];
#pragma unroll
            for (int g = 0; g < 4; ++g)           // regs 1..3 undefined
                acc2[g][0] = b2v[g];
#pragma unroll
            for (int kt = 0; kt < 4; ++kt)
#pragma unroll
                for (int g = 0; g < 4; ++g) acc2[g] = mfma16(a[kt], b2f[g][kt], acc2[g]);
            a0c = a[0]; a1c = a[1];               // h1(t) becomes MFMA1(t+1)'s A

            // ---- epilogue 2 (1 row), writes h2_t -> buf[1-p] ----
            {
                float ig = sigm_e(acc2[0][0]);
                float fg = sigm_e(acc2[1][0]);
                float gv = tanh_e(acc2[2][0]);
                float og = sigm_e(acc2[3][0]);
                c2 = fg * c2 + ig * gv;
                h2v = og * tanh_e(c2);
                Abuf[(1 - p) * 2048 + 1024 + ((u >> 3) * 16 + 4 * q) * 8 + (u & 7)] = (f16)h2v;
            }
        }
        tokc = tokn;
    }

    // ---- head: out[row] = sigmoid(sum_u h2[row][u]*Wd[u] + bd) ----
    {
        float pv = h2v * wdv;
        pv += __shfl_xor(pv, 1, 64);
        pv += __shfl_xor(pv, 2, 64);
        pv += __shfl_xor(pv, 4, 64);
        pv += __shfl_xor(pv, 8, 64);
        if (li == 0) red[w * 4 + q] = pv;         // per-wave partial for local row
    }
    __syncthreads();
    if (tid < 4) {
        float sum = red[tid] + red[4 + tid] + red[8 + tid] + red[12 + tid] + bdv;
        out[row0 + tid] = sigm_exact(sum);
    }
}

// ---------------- fallback (no workspace): round-1 monolithic ----------------
__device__ __forceinline__ float lane_bcast(float v, int j) {
    return __builtin_bit_cast(float, __builtin_amdgcn_readlane(__builtin_bit_cast(int, v), j));
}
__device__ __forceinline__ float sigm_f(float x)  { return 1.0f / (1.0f + __expf(-x)); }
__device__ __forceinline__ float tanh_f(float x)  { return 2.0f / (1.0f + __expf(-2.0f * x)) - 1.0f; }

__global__ __launch_bounds__(512) void lstm_fused_fallback(
    const int* __restrict__ tokens, const float* __restrict__ emb,
    const float* __restrict__ W1, const float* __restrict__ U1, const float* __restrict__ b1,
    const float* __restrict__ W2, const float* __restrict__ U2, const float* __restrict__ b2,
    const float* __restrict__ Wd, const float* __restrict__ bd, float* __restrict__ out) {
    const int lane = threadIdx.x & 63;
    const int wave = threadIdx.x >> 6;
    const int row0 = blockIdx.x * 16 + wave * 2;
    float bias1[4], bias2[4];
#pragma unroll
    for (int g = 0; g < 4; ++g) { bias1[g] = b1[g * 64 + lane]; bias2[g] = b2[g * 64 + lane]; }
    const float wd = Wd[lane]; const float bdv = bd[0];
    float h1[2] = {0.f, 0.f}, c1[2] = {0.f, 0.f}, h2[2] = {0.f, 0.f}, c2[2] = {0.f, 0.f};
#pragma unroll 1
    for (int t = 0; t < SEQ; ++t) {
        float acc[4][2];
#pragma unroll
        for (int g = 0; g < 4; ++g) { acc[g][0] = bias1[g]; acc[g][1] = bias1[g]; }
        int tokA = __builtin_amdgcn_readfirstlane(tokens[(row0 + 0) * SEQ + t]);
        int tokB = __builtin_amdgcn_readfirstlane(tokens[(row0 + 1) * SEQ + t]);
        const float4* xA = (const float4*)(emb + (size_t)tokA * EMB);
        const float4* xB = (const float4*)(emb + (size_t)tokB * EMB);
#pragma unroll 5
        for (int d4 = 0; d4 < EMB / 4; ++d4) {
            float4 a4 = xA[d4]; float4 b4 = xB[d4];
            float av[4] = {a4.x, a4.y, a4.z, a4.w}; float bv[4] = {b4.x, b4.y, b4.z, b4.w};
#pragma unroll
            for (int e = 0; e < 4; ++e) {
                const float* wrow = W1 + (d4 * 4 + e) * 256;
#pragma unroll
                for (int g = 0; g < 4; ++g) {
                    float wv = wrow[g * 64 + lane];
                    acc[g][0] += av[e] * wv; acc[g][1] += bv[e] * wv;
                }
            }
        }
#pragma unroll 4
        for (int j = 0; j < 64; ++j) {
            float ha = lane_bcast(h1[0], j), hb = lane_bcast(h1[1], j);
            const float* urow = U1 + j * 256;
#pragma unroll
            for (int g = 0; g < 4; ++g) {
                float wv = urow[g * 64 + lane];
                acc[g][0] += ha * wv; acc[g][1] += hb * wv;
            }
        }
#pragma unroll
        for (int r = 0; r < 2; ++r) {
            float ig = sigm_f(acc[0][r]), fg = sigm_f(acc[1][r]);
            float gg = tanh_f(acc[2][r]), og = sigm_f(acc[3][r]);
            c1[r] = fg * c1[r] + ig * gg; h1[r] = og * tanh_f(c1[r]);
        }
        float acc2[4][2];
#pragma unroll
        for (int g = 0; g < 4; ++g) { acc2[g][0] = bias2[g]; acc2[g][1] = bias2[g]; }
#pragma unroll 4
        for (int j = 0; j < 64; ++j) {
            float pa = lane_bcast(h1[0], j), pb = lane_bcast(h1[1], j);
            float qa = lane_bcast(h2[0], j), qb = lane_bcast(h2[1], j);
            const float* w2row = W2 + j * 256; const float* u2row = U2 + j * 256;
#pragma unroll
            for (int g = 0; g < 4; ++g) {
                float w2v = w2row[g * 64 + lane], u2v = u2row[g * 64 + lane];
                acc2[g][0] += pa * w2v + qa * u2v;
                acc2[g][1] += pb * w2v + qb * u2v;
            }
        }
#pragma unroll
        for (int r = 0; r < 2; ++r) {
            float ig = sigm_f(acc2[0][r]), fg = sigm_f(acc2[1][r]);
            float gg = tanh_f(acc2[2][r]), og = sigm_f(acc2[3][r]);
            c2[r] = fg * c2[r] + ig * gg; h2[r] = og * tanh_f(c2[r]);
        }
    }
#pragma unroll
    for (int r = 0; r < 2; ++r) {
        float p = h2[r] * wd;
#pragma unroll
        for (int off = 32; off > 0; off >>= 1) p += __shfl_down(p, off, 64);
        if (lane == 0) out[row0 + r] = sigm_f(p + bdv);
    }
}

extern "C" void kernel_launch(void* const* d_in, const int* in_sizes, int n_in,
                              void* d_out, int out_size, void* d_ws, size_t ws_size,
                              hipStream_t stream) {
    const int*   tokens = (const int*)  d_in[0];
    const float* emb    = (const float*)d_in[1];
    const float* W1     = (const float*)d_in[2];
    const float* U1     = (const float*)d_in[3];
    const float* b1     = (const float*)d_in[4];
    const float* W2     = (const float*)d_in[5];
    const float* U2     = (const float*)d_in[6];
    const float* b2     = (const float*)d_in[7];
    const float* Wd     = (const float*)d_in[8];
    const float* bd     = (const float*)d_in[9];
    float* out = (float*)d_out;

    if (ws_size < (size_t)WS_NEEDED) {
        lstm_fused_fallback<<<256, 512, 0, stream>>>(tokens, emb, W1, U1, b1, W2, U2, b2, Wd, bd, out);
        return;
    }

    char*  ws  = (char*)d_ws;
    float* E1f = (float*)(ws + WS_E1F_OFF);
    uint*  B1f = (uint*) (ws + WS_B1F_OFF);
    uint*  B2f = (uint*) (ws + WS_B2F_OFF);

    prep_e1  <<<NB_E1 + 64, 256, 0, stream>>>(emb, W1, U1, b1, W2, U2, E1f, B1f, B2f);
    lstm_mfma<<<NGRID, 256, 0, stream>>>(tokens, (const f32x4*)E1f,
                                         (const uint4*)B1f, (const uint4*)B2f,
                                         b2, Wd, bd, out);
}

// Round 11
// 199.550 us; speedup vs baseline: 4.5111x; 4.5111x over previous
//
#include <hip/hip_runtime.h>

// LstmSequential round 11: r10's 4-rows/block TLP shape, WITHOUT the r10 spill.
// r10 post-mortem: __launch_bounds__(256,4) made the compiler split the 128-reg
// budget into 64 arch + 64 acc and spill the 96 weight-fragment VGPRs to scratch
// (VGPR_Count=64, 2.8GB FETCH). Fix: keep grid=1024 x 4 rows but declare
// __launch_bounds__(256,2) (the bound that gave VGPR=112, zero spill, in r8).
// Natural register demand of the 1-row body is ~96-112 <= 128, so the HARDWARE
// gives 4 waves/SIMD (m69: occupancy steps at vgpr<=128) without forcing the
// allocator. Per-CU rows unchanged (4x4=16); MFMA/CU doubles (issue budget ok);
// 4 independent blocks/CU fill barrier + dep-chain bubbles.
// Everything else = r8: split prep kernel, 1 lgkm-only barrier/step, register-
// cached h1 frags, depth-2 f32 E1 gather folded into MFMA acc init, exp2 acts.
// Fallback to round-1 monolithic kernel if ws too small.

#define VOCAB 10000
#define EMB   100
#define SEQ   80
#define BATCH 4096
#define NGRID 1024                   // 4 rows/block

typedef _Float16 f16;
typedef _Float16 f16x8 __attribute__((ext_vector_type(8)));
typedef _Float16 half2_t __attribute__((ext_vector_type(2)));
typedef float    f32x4 __attribute__((ext_vector_type(4)));
typedef unsigned int uint;

#define LOG2E 1.4426950408889634f

__device__ __forceinline__ uint pack2(float lo, float hi) {
    return __builtin_bit_cast(uint, __builtin_amdgcn_cvt_pkrtz(lo, hi));
}
__device__ __forceinline__ uint rl_u(uint v, int l) { return (uint)__builtin_amdgcn_readlane((int)v, l); }
__device__ __forceinline__ float dot2(uint a, uint b, float c) {
    return __builtin_amdgcn_fdot2(__builtin_bit_cast(half2_t, a), __builtin_bit_cast(half2_t, b), c, false);
}
__device__ __forceinline__ f32x4 mfma16(uint4 a, uint4 b, f32x4 c) {
    return __builtin_amdgcn_mfma_f32_16x16x32_f16(
        __builtin_bit_cast(f16x8, a), __builtin_bit_cast(f16x8, b), c, 0, 0, 0);
}
// Barrier draining ONLY LDS ops — global gathers stay outstanding.
__device__ __forceinline__ void barrier_lds() {
    asm volatile("s_waitcnt lgkmcnt(0)\n\ts_barrier" ::: "memory");
}
__device__ __forceinline__ float sigm_e(float x) {
    float t = __builtin_amdgcn_exp2f(-LOG2E * x);
    return __builtin_amdgcn_rcpf(1.0f + t);
}
__device__ __forceinline__ float tanh_e(float x) {
    float t = __builtin_amdgcn_exp2f((2.0f * LOG2E) * x);
    return __builtin_fmaf(-2.0f, __builtin_amdgcn_rcpf(1.0f + t), 1.0f);
}
__device__ __forceinline__ float sigm_exact(float x) {
    return 1.0f / (1.0f + __expf(-x));
}

// ---------------- workspace layout (bytes) ----------------
#define WS_E1F_OFF 0                 // VOCAB*256 f32  = 10,240,000
#define WS_B1F_OFF 10240000          // 2048 uint4     = 32,768
#define WS_B2F_OFF 10272768          // 4096 uint4     = 65,536
#define WS_NEEDED  10338304

// ---------------- prep_e1: E1 table + B-fragment packing (split, r8) ----------------
#define NB_E1 512
__global__ __launch_bounds__(256) void prep_e1(
    const float* __restrict__ emb,
    const float* __restrict__ W1, const float* __restrict__ U1,
    const float* __restrict__ b1,
    const float* __restrict__ W2, const float* __restrict__ U2,
    float* __restrict__ E1f, uint* __restrict__ B1f, uint* __restrict__ B2f) {
    if (blockIdx.x < NB_E1) {
        // role A: thread c owns raw col c (coalesced W1 loads); store applies the
        // [v][u][g] permutation: E1f[v*256 + u*4 + g].
        const int c    = threadIdx.x;
        const int lane = c & 63;
        uint w[50];
#pragma unroll
        for (int kp = 0; kp < 50; ++kp)
            w[kp] = pack2(W1[(2 * kp) * 256 + c], W1[(2 * kp + 1) * 256 + c]);
        const float bias = b1[c];
        const int   dst  = (c & 63) * 4 + (c >> 6);
        float2 ecur = {0.f, 0.f};
        if (lane < 50) ecur = *(const float2*)(emb + (size_t)blockIdx.x * EMB + 2 * lane);
        for (int v = blockIdx.x; v < VOCAB; v += NB_E1) {
            float2 enext = {0.f, 0.f};
            if (v + NB_E1 < VOCAB && lane < 50)
                enext = *(const float2*)(emb + (size_t)(v + NB_E1) * EMB + 2 * lane);
            uint ep = pack2(ecur.x, ecur.y);
            float a0 = bias, a1 = 0.0f;
#pragma unroll
            for (int kp = 0; kp < 50; kp += 2) {
                a0 = dot2(w[kp],     rl_u(ep, kp),     a0);
                a1 = dot2(w[kp + 1], rl_u(ep, kp + 1), a1);
            }
            E1f[v * 256 + dst] = a0 + a1;
            ecur = enext;
        }
    } else {
        // role B: B-fragment packing (16x16x32 f16 layout: lane holds
        // B[k = kt*32 + (lane>>4)*8 + j][n = lane&15], dword dw: j=2dw lo, 2dw+1 hi)
        int idx = (blockIdx.x - NB_E1) * 256 + threadIdx.x;   // 0..16383
        if (idx < 8192) {                                     // B1f (U1, 64x256)
            int dw = idx & 3, lane = (idx >> 2) & 63, kt = (idx >> 8) & 1,
                g = (idx >> 9) & 3, w = idx >> 11;
            int k   = kt * 32 + (lane >> 4) * 8 + dw * 2;
            int col = g * 64 + w * 16 + (lane & 15);
            B1f[idx] = pack2(U1[k * 256 + col], U1[(k + 1) * 256 + col]);
        }
        if (idx < 16384) {                                    // B2f ([W2;U2], 128x256)
            int dw = idx & 3, lane = (idx >> 2) & 63, kt = (idx >> 8) & 3,
                g = (idx >> 10) & 3, w = idx >> 12;
            int k   = kt * 32 + (lane >> 4) * 8 + dw * 2;
            int col = g * 64 + w * 16 + (lane & 15);
            float lo = (k < 64) ? W2[k * 256 + col] : U2[(k - 64) * 256 + col];
            float hi = (k < 63) ? W2[(k + 1) * 256 + col] : U2[(k + 1 - 64) * 256 + col];
            B2f[idx] = pack2(lo, hi);
        }
    }
}

// ---------------- fused 2-layer LSTM + head, 4 rows/block ----------------
// A-buffer (ping-pong buf b): fp16 A-matrix [16 m x 128 k] in fragment layout,
//   f16 index of (m,k) = ((k>>3)*16 + m)*8 + (k&7); lane's kt-frag = uint4 [kt*64+lane].
//   k 0..63 = h1, k 64..127 = h2. Batch row (row0+q) at tile-row 4q; rows 4q+1..3
//   stay zero forever (acc regs 1..3 garbage, never read).
// Step t (p = t&1): MFMA1 uses register-cached h1(t-1) frags | epi1 writes
//   buf[1-p].h1 | gather e1(t+2) | BARRIER | MFMA2 ds_reads buf[1-p].h1 (cached for
//   next step) + buf[p].h2 | epi2 writes buf[1-p].h2.
// NOTE: bound is (256,2) — NOT (256,4): the tighter bound made the allocator split
// 64 arch + 64 acc and spill the weight frags (r10, 8.7x regression). At ~112 regs
// the HW gives 4 waves/SIMD on its own.
__global__ __launch_bounds__(256, 2) void lstm_mfma(
    const int* __restrict__ tokens, const f32x4* __restrict__ E1f4,
    const uint4* __restrict__ B1f, const uint4* __restrict__ B2f,
    const float* __restrict__ b2, const float* __restrict__ Wd,
    const float* __restrict__ bd, float* __restrict__ out) {
    __shared__ uint4 AbufU[512];                  // 2 bufs x 256 uint4 = 8 KB
    __shared__ float red[16];
    f16* Abuf = (f16*)AbufU;

    const int tid  = threadIdx.x;
    const int w    = tid >> 6;
    const int lane = tid & 63;
    const int q    = lane >> 4;
    const int li   = lane & 15;
    const int u    = w * 16 + li;                 // this lane's unit (output col)
    const int row0 = blockIdx.x * 4;
    const int row  = row0 + q;                    // this lane's batch row (tile-row 4q)

    const uint4 z4 = {0u, 0u, 0u, 0u};
    AbufU[tid] = z4; AbufU[tid + 256] = z4;       // zero both buffers

    // persistent B fragments (96 VGPRs)
    uint4 b1f[4][2], b2f[4][4];
#pragma unroll
    for (int g = 0; g < 4; ++g) {
#pragma unroll
        for (int kt = 0; kt < 2; ++kt) b1f[g][kt] = B1f[((w * 4 + g) * 2 + kt) * 64 + lane];
#pragma unroll
        for (int kt = 0; kt < 4; ++kt) b2f[g][kt] = B2f[((w * 4 + g) * 4 + kt) * 64 + lane];
    }
    float b2v[4];
#pragma unroll
    for (int g = 0; g < 4; ++g) b2v[g] = b2[g * 64 + u];
    const float wdv = Wd[u];
    const float bdv = bd[0];

    // token window + depth-2 E1 prefetch (1 row/lane)
    int4  tokc, tokn;
    f32x4 e1buf[2];
    tokc = *(const int4*)(tokens + (size_t)row * SEQ);
    e1buf[0] = E1f4[(size_t)tokc.x * 64 + u];
    e1buf[1] = E1f4[(size_t)tokc.y * 64 + u];

    float c1 = 0.f, c2 = 0.f, h2v = 0.f;
    uint4 a0c = z4, a1c = z4;                     // cached h1(t-1) A-frags

    __syncthreads();                              // init barrier (full drain, once)

#pragma unroll 1
    for (int t4 = 0; t4 < SEQ / 4; ++t4) {
        if (t4 < SEQ / 4 - 1)
            tokn = *(const int4*)(tokens + (size_t)row * SEQ + (t4 + 1) * 4);
#pragma unroll
        for (int s = 0; s < 4; ++s) {
            const int p = s & 1;                  // == t&1
            // ---- layer 1 MFMA: z1 = e1 (in C) + h1_{t-1} @ U1 — pure registers ----
            f32x4 acc[4];
#pragma unroll
            for (int g = 0; g < 4; ++g)           // regs 1..3 undefined (dead rows)
                acc[g][0] = e1buf[p][g];
#pragma unroll
            for (int g = 0; g < 4; ++g) acc[g] = mfma16(a0c, b1f[g][0], acc[g]);
#pragma unroll
            for (int g = 0; g < 4; ++g) acc[g] = mfma16(a1c, b1f[g][1], acc[g]);

            // ---- epilogue 1 (1 row), writes h1_t -> buf[1-p] ----
            {
                float ig = sigm_e(acc[0][0]);
                float fg = sigm_e(acc[1][0]);
                float gv = tanh_e(acc[2][0]);
                float og = sigm_e(acc[3][0]);
                c1 = fg * c1 + ig * gv;
                float h1 = og * tanh_e(c1);
                Abuf[(1 - p) * 2048 + ((u >> 3) * 16 + 4 * q) * 8 + (u & 7)] = (f16)h1;
            }

            // gather e1 for t+2 (registers only — pre-barrier, max in-flight)
            if (t4 * 4 + s + 2 < SEQ) {
                int tk = (s == 0) ? tokc.z : (s == 1) ? tokc.w
                       : (s == 2) ? tokn.x : tokn.y;
                e1buf[p] = E1f4[(size_t)tk * 64 + u];
            }

            barrier_lds();                        // lgkm-only: gathers stay in flight

            // ---- layer 2 MFMA: z2 = b2 (in C) + [h1_t | h2_{t-1}] @ [W2;U2] ----
            uint4 a[4];
            a[0] = AbufU[(1 - p) * 256 + lane];   // h1(t) — cached for next MFMA1
            a[1] = AbufU[(1 - p) * 256 + 64 + lane];
            a[2] = AbufU[p * 256 + 128 + lane];   // h2(t-1)
            a[3] = AbufU[p * 256 + 192 + lane];
            f32x4 acc2[4];
#pragma unroll
            for (int g = 0; g < 4; ++g)           // regs 1..3 undefined
                acc2[g][0] = b2v[g];
#pragma unroll
            for (int kt = 0; kt < 4; ++kt)
#pragma unroll
                for (int g = 0; g < 4; ++g) acc2[g] = mfma16(a[kt], b2f[g][kt], acc2[g]);
            a0c = a[0]; a1c = a[1];               // h1(t) becomes MFMA1(t+1)'s A

            // ---- epilogue 2 (1 row), writes h2_t -> buf[1-p] ----
            {
                float ig = sigm_e(acc2[0][0]);
                float fg = sigm_e(acc2[1][0]);
                float gv = tanh_e(acc2[2][0]);
                float og = sigm_e(acc2[3][0]);
                c2 = fg * c2 + ig * gv;
                h2v = og * tanh_e(c2);
                Abuf[(1 - p) * 2048 + 1024 + ((u >> 3) * 16 + 4 * q) * 8 + (u & 7)] = (f16)h2v;
            }
        }
        tokc = tokn;
    }

    // ---- head: out[row] = sigmoid(sum_u h2[row][u]*Wd[u] + bd) ----
    {
        float pv = h2v * wdv;
        pv += __shfl_xor(pv, 1, 64);
        pv += __shfl_xor(pv, 2, 64);
        pv += __shfl_xor(pv, 4, 64);
        pv += __shfl_xor(pv, 8, 64);
        if (li == 0) red[w * 4 + q] = pv;         // per-wave partial for local row
    }
    __syncthreads();
    if (tid < 4) {
        float sum = red[tid] + red[4 + tid] + red[8 + tid] + red[12 + tid] + bdv;
        out[row0 + tid] = sigm_exact(sum);
    }
}

// ---------------- fallback (no workspace): round-1 monolithic ----------------
__device__ __forceinline__ float lane_bcast(float v, int j) {
    return __builtin_bit_cast(float, __builtin_amdgcn_readlane(__builtin_bit_cast(int, v), j));
}
__device__ __forceinline__ float sigm_f(float x)  { return 1.0f / (1.0f + __expf(-x)); }
__device__ __forceinline__ float tanh_f(float x)  { return 2.0f / (1.0f + __expf(-2.0f * x)) - 1.0f; }

__global__ __launch_bounds__(512) void lstm_fused_fallback(
    const int* __restrict__ tokens, const float* __restrict__ emb,
    const float* __restrict__ W1, const float* __restrict__ U1, const float* __restrict__ b1,
    const float* __restrict__ W2, const float* __restrict__ U2, const float* __restrict__ b2,
    const float* __restrict__ Wd, const float* __restrict__ bd, float* __restrict__ out) {
    const int lane = threadIdx.x & 63;
    const int wave = threadIdx.x >> 6;
    const int row0 = blockIdx.x * 16 + wave * 2;
    float bias1[4], bias2[4];
#pragma unroll
    for (int g = 0; g < 4; ++g) { bias1[g] = b1[g * 64 + lane]; bias2[g] = b2[g * 64 + lane]; }
    const float wd = Wd[lane]; const float bdv = bd[0];
    float h1[2] = {0.f, 0.f}, c1[2] = {0.f, 0.f}, h2[2] = {0.f, 0.f}, c2[2] = {0.f, 0.f};
#pragma unroll 1
    for (int t = 0; t < SEQ; ++t) {
        float acc[4][2];
#pragma unroll
        for (int g = 0; g < 4; ++g) { acc[g][0] = bias1[g]; acc[g][1] = bias1[g]; }
        int tokA = __builtin_amdgcn_readfirstlane(tokens[(row0 + 0) * SEQ + t]);
        int tokB = __builtin_amdgcn_readfirstlane(tokens[(row0 + 1) * SEQ + t]);
        const float4* xA = (const float4*)(emb + (size_t)tokA * EMB);
        const float4* xB = (const float4*)(emb + (size_t)tokB * EMB);
#pragma unroll 5
        for (int d4 = 0; d4 < EMB / 4; ++d4) {
            float4 a4 = xA[d4]; float4 b4 = xB[d4];
            float av[4] = {a4.x, a4.y, a4.z, a4.w}; float bv[4] = {b4.x, b4.y, b4.z, b4.w};
#pragma unroll
            for (int e = 0; e < 4; ++e) {
                const float* wrow = W1 + (d4 * 4 + e) * 256;
#pragma unroll
                for (int g = 0; g < 4; ++g) {
                    float wv = wrow[g * 64 + lane];
                    acc[g][0] += av[e] * wv; acc[g][1] += bv[e] * wv;
                }
            }
        }
#pragma unroll 4
        for (int j = 0; j < 64; ++j) {
            float ha = lane_bcast(h1[0], j), hb = lane_bcast(h1[1], j);
            const float* urow = U1 + j * 256;
#pragma unroll
            for (int g = 0; g < 4; ++g) {
                float wv = urow[g * 64 + lane];
                acc[g][0] += ha * wv; acc[g][1] += hb * wv;
            }
        }
#pragma unroll
        for (int r = 0; r < 2; ++r) {
            float ig = sigm_f(acc[0][r]), fg = sigm_f(acc[1][r]);
            float gg = tanh_f(acc[2][r]), og = sigm_f(acc[3][r]);
            c1[r] = fg * c1[r] + ig * gg; h1[r] = og * tanh_f(c1[r]);
        }
        float acc2[4][2];
#pragma unroll
        for (int g = 0; g < 4; ++g) { acc2[g][0] = bias2[g]; acc2[g][1] = bias2[g]; }
#pragma unroll 4
        for (int j = 0; j < 64; ++j) {
            float pa = lane_bcast(h1[0], j), pb = lane_bcast(h1[1], j);
            float qa = lane_bcast(h2[0], j), qb = lane_bcast(h2[1], j);
            const float* w2row = W2 + j * 256; const float* u2row = U2 + j * 256;
#pragma unroll
            for (int g = 0; g < 4; ++g) {
                float w2v = w2row[g * 64 + lane], u2v = u2row[g * 64 + lane];
                acc2[g][0] += pa * w2v + qa * u2v;
                acc2[g][1] += pb * w2v + qb * u2v;
            }
        }
#pragma unroll
        for (int r = 0; r < 2; ++r) {
            float ig = sigm_f(acc2[0][r]), fg = sigm_f(acc2[1][r]);
            float gg = tanh_f(acc2[2][r]), og = sigm_f(acc2[3][r]);
            c2[r] = fg * c2[r] + ig * gg; h2[r] = og * tanh_f(c2[r]);
        }
    }
#pragma unroll
    for (int r = 0; r < 2; ++r) {
        float p = h2[r] * wd;
#pragma unroll
        for (int off = 32; off > 0; off >>= 1) p += __shfl_down(p, off, 64);
        if (lane == 0) out[row0 + r] = sigm_f(p + bdv);
    }
}

extern "C" void kernel_launch(void* const* d_in, const int* in_sizes, int n_in,
                              void* d_out, int out_size, void* d_ws, size_t ws_size,
                              hipStream_t stream) {
    const int*   tokens = (const int*)  d_in[0];
    const float* emb    = (const float*)d_in[1];
    const float* W1     = (const float*)d_in[2];
    const float* U1     = (const float*)d_in[3];
    const float* b1     = (const float*)d_in[4];
    const float* W2     = (const float*)d_in[5];
    const float* U2     = (const float*)d_in[6];
    const float* b2     = (const float*)d_in[7];
    const float* Wd     = (const float*)d_in[8];
    const float* bd     = (const float*)d_in[9];
    float* out = (float*)d_out;

    if (ws_size < (size_t)WS_NEEDED) {
        lstm_fused_fallback<<<256, 512, 0, stream>>>(tokens, emb, W1, U1, b1, W2, U2, b2, Wd, bd, out);
        return;
    }

    char*  ws  = (char*)d_ws;
    float* E1f = (float*)(ws + WS_E1F_OFF);
    uint*  B1f = (uint*) (ws + WS_B1F_OFF);
    uint*  B2f = (uint*) (ws + WS_B2F_OFF);

    prep_e1  <<<NB_E1 + 64, 256, 0, stream>>>(emb, W1, U1, b1, W2, U2, E1f, B1f, B2f);
    lstm_mfma<<<NGRID, 256, 0, stream>>>(tokens, (const f32x4*)E1f,
                                         (const uint4*)B1f, (const uint4*)B2f,
                                         b2, Wd, bd, out);
}

// Round 12
// 174.012 us; speedup vs baseline: 5.1732x; 1.1468x over previous
//
#include <hip/hip_runtime.h>

// LstmSequential round 12: cross-step software pipelining — layer 2 runs one step
// behind layer 1, so BOTH MFMAs consume fragments ds_read after the PREVIOUS
// barrier (full step of latency hiding), the two epilogues are independent chains,
// and the barrier moves to the end of the step.
//   iteration t: MFMA1(t)[h1(t-1)] ; MFMA2(t-1)[h1(t-1),h2(t-2)] ; epi1(t)->buf[p].h1 ;
//                epi2(t-1)->buf[p].h2 (skipped at t=0: h2(-1)=0) ; gather e1(t+2) ;
//                BARRIER(lgkm-only) ; ds_read buf[p] -> h1(t),h2(t-1) frags.
//   tail: MFMA2(79)+epi2(79) in registers -> head.
// Hazards (p=t&1): buf[p] written pre-B(t), read post-B(t) (RAW crosses B(t));
// rewritten at t+2 after B(t+1), reads drained before B(t+1) via lgkmcnt(0) (WAR ok).
// Shape = r8 (the measured argmin of the occupancy family; r6/r10/r11 all worse):
// 512 blocks x 4 waves, 8 rows/block at tile-rows {4q,4q+1}, __launch_bounds__(256,2)
// (NOT (256,4): r10 showed it forces a 64/64 reg split and spills the weight frags),
// f32 E1 gather folded into MFMA acc init, exp2 activations, depth-2 E1 prefetch.
// Fallback to round-1 monolithic kernel if ws too small.

#define VOCAB 10000
#define EMB   100
#define SEQ   80
#define BATCH 4096
#define NGRID 512

typedef _Float16 f16;
typedef _Float16 f16x8 __attribute__((ext_vector_type(8)));
typedef _Float16 half2_t __attribute__((ext_vector_type(2)));
typedef float    f32x4 __attribute__((ext_vector_type(4)));
typedef unsigned int uint;

#define LOG2E 1.4426950408889634f

__device__ __forceinline__ uint pack2(float lo, float hi) {
    return __builtin_bit_cast(uint, __builtin_amdgcn_cvt_pkrtz(lo, hi));
}
__device__ __forceinline__ uint rl_u(uint v, int l) { return (uint)__builtin_amdgcn_readlane((int)v, l); }
__device__ __forceinline__ float dot2(uint a, uint b, float c) {
    return __builtin_amdgcn_fdot2(__builtin_bit_cast(half2_t, a), __builtin_bit_cast(half2_t, b), c, false);
}
__device__ __forceinline__ f32x4 mfma16(uint4 a, uint4 b, f32x4 c) {
    return __builtin_amdgcn_mfma_f32_16x16x32_f16(
        __builtin_bit_cast(f16x8, a), __builtin_bit_cast(f16x8, b), c, 0, 0, 0);
}
// Barrier draining ONLY LDS ops — global gathers stay outstanding.
__device__ __forceinline__ void barrier_lds() {
    asm volatile("s_waitcnt lgkmcnt(0)\n\ts_barrier" ::: "memory");
}
__device__ __forceinline__ float sigm_e(float x) {
    float t = __builtin_amdgcn_exp2f(-LOG2E * x);
    return __builtin_amdgcn_rcpf(1.0f + t);
}
__device__ __forceinline__ float tanh_e(float x) {
    float t = __builtin_amdgcn_exp2f((2.0f * LOG2E) * x);
    return __builtin_fmaf(-2.0f, __builtin_amdgcn_rcpf(1.0f + t), 1.0f);
}
__device__ __forceinline__ float sigm_exact(float x) {
    return 1.0f / (1.0f + __expf(-x));
}

// ---------------- workspace layout (bytes) ----------------
#define WS_E1F_OFF 0                 // VOCAB*256 f32  = 10,240,000
#define WS_B1F_OFF 10240000          // 2048 uint4     = 32,768
#define WS_B2F_OFF 10272768          // 4096 uint4     = 65,536
#define WS_NEEDED  10338304

// ---------------- prep_e1: E1 table + B-fragment packing (unchanged from r8) ----------------
#define NB_E1 512
__global__ __launch_bounds__(256) void prep_e1(
    const float* __restrict__ emb,
    const float* __restrict__ W1, const float* __restrict__ U1,
    const float* __restrict__ b1,
    const float* __restrict__ W2, const float* __restrict__ U2,
    float* __restrict__ E1f, uint* __restrict__ B1f, uint* __restrict__ B2f) {
    if (blockIdx.x < NB_E1) {
        // role A: thread c owns raw col c (coalesced W1 loads); store applies the
        // [v][u][g] permutation: E1f[v*256 + u*4 + g].
        const int c    = threadIdx.x;
        const int lane = c & 63;
        uint w[50];
#pragma unroll
        for (int kp = 0; kp < 50; ++kp)
            w[kp] = pack2(W1[(2 * kp) * 256 + c], W1[(2 * kp + 1) * 256 + c]);
        const float bias = b1[c];
        const int   dst  = (c & 63) * 4 + (c >> 6);
        float2 ecur = {0.f, 0.f};
        if (lane < 50) ecur = *(const float2*)(emb + (size_t)blockIdx.x * EMB + 2 * lane);
        for (int v = blockIdx.x; v < VOCAB; v += NB_E1) {
            float2 enext = {0.f, 0.f};
            if (v + NB_E1 < VOCAB && lane < 50)
                enext = *(const float2*)(emb + (size_t)(v + NB_E1) * EMB + 2 * lane);
            uint ep = pack2(ecur.x, ecur.y);
            float a0 = bias, a1 = 0.0f;
#pragma unroll
            for (int kp = 0; kp < 50; kp += 2) {
                a0 = dot2(w[kp],     rl_u(ep, kp),     a0);
                a1 = dot2(w[kp + 1], rl_u(ep, kp + 1), a1);
            }
            E1f[v * 256 + dst] = a0 + a1;
            ecur = enext;
        }
    } else {
        // role B: B-fragment packing (16x16x32 f16 layout: lane holds
        // B[k = kt*32 + (lane>>4)*8 + j][n = lane&15], dword dw: j=2dw lo, 2dw+1 hi)
        int idx = (blockIdx.x - NB_E1) * 256 + threadIdx.x;   // 0..16383
        if (idx < 8192) {                                     // B1f (U1, 64x256)
            int dw = idx & 3, lane = (idx >> 2) & 63, kt = (idx >> 8) & 1,
                g = (idx >> 9) & 3, w = idx >> 11;
            int k   = kt * 32 + (lane >> 4) * 8 + dw * 2;
            int col = g * 64 + w * 16 + (lane & 15);
            B1f[idx] = pack2(U1[k * 256 + col], U1[(k + 1) * 256 + col]);
        }
        if (idx < 16384) {                                    // B2f ([W2;U2], 128x256)
            int dw = idx & 3, lane = (idx >> 2) & 63, kt = (idx >> 8) & 3,
                g = (idx >> 10) & 3, w = idx >> 12;
            int k   = kt * 32 + (lane >> 4) * 8 + dw * 2;
            int col = g * 64 + w * 16 + (lane & 15);
            float lo = (k < 64) ? W2[k * 256 + col] : U2[(k - 64) * 256 + col];
            float hi = (k < 63) ? W2[(k + 1) * 256 + col] : U2[(k + 1 - 64) * 256 + col];
            B2f[idx] = pack2(lo, hi);
        }
    }
}

// ---------------- fused 2-layer LSTM + head, cross-step pipelined ----------------
// A-buffer (2 bufs, index by p=t&1): fp16 A-matrix [16 m x 128 k] in fragment layout,
//   f16 index of (m,k) = ((k>>3)*16 + m)*8 + (k&7); lane's kt-frag = uint4 [kt*64+lane].
//   k 0..63 = h1, k 64..127 = h2. Rows at tile-rows {4q, 4q+1}; {4q+2,4q+3} dead.
__global__ __launch_bounds__(256, 2) void lstm_mfma(
    const int* __restrict__ tokens, const f32x4* __restrict__ E1f4,
    const uint4* __restrict__ B1f, const uint4* __restrict__ B2f,
    const float* __restrict__ b2, const float* __restrict__ Wd,
    const float* __restrict__ bd, float* __restrict__ out) {
    __shared__ uint4 AbufU[512];                  // 2 bufs x 256 uint4 = 8 KB
    __shared__ float red[32];
    f16* Abuf = (f16*)AbufU;

    const int tid  = threadIdx.x;
    const int w    = tid >> 6;
    const int lane = tid & 63;
    const int q    = lane >> 4;
    const int li   = lane & 15;
    const int u    = w * 16 + li;                 // this lane's unit (output col)
    const int row0 = blockIdx.x * 8;

    const uint4 z4 = {0u, 0u, 0u, 0u};
    AbufU[tid] = z4; AbufU[tid + 256] = z4;       // zero both buffers (h2(-1)=0 read)

    // persistent B fragments (96 VGPRs)
    uint4 b1f[4][2], b2f[4][4];
#pragma unroll
    for (int g = 0; g < 4; ++g) {
#pragma unroll
        for (int kt = 0; kt < 2; ++kt) b1f[g][kt] = B1f[((w * 4 + g) * 2 + kt) * 64 + lane];
#pragma unroll
        for (int kt = 0; kt < 4; ++kt) b2f[g][kt] = B2f[((w * 4 + g) * 4 + kt) * 64 + lane];
    }
    float b2v[4];
#pragma unroll
    for (int g = 0; g < 4; ++g) b2v[g] = b2[g * 64 + u];
    const float wdv = Wd[u];
    const float bdv = bd[0];

    // token window + depth-2 E1 prefetch (e1buf[t&1] holds step t's rows)
    int4  tokc[2], tokn[2];
    f32x4 e1buf[2][2];
#pragma unroll
    for (int r = 0; r < 2; ++r) {
        tokc[r] = *(const int4*)(tokens + (size_t)(row0 + q * 2 + r) * SEQ);
        e1buf[0][r] = E1f4[(size_t)tokc[r].x * 64 + u];
        e1buf[1][r] = E1f4[(size_t)tokc[r].y * 64 + u];
    }

    float c1[2] = {0.f, 0.f}, c2[2] = {0.f, 0.f};
    float h2v[2] = {0.f, 0.f};
    // pipelined fragment registers: h1(t-1) and h2(t-2) (seeded 0 for t=0)
    uint4 a1f0 = z4, a1f1 = z4, a2f0 = z4, a2f1 = z4;

    __syncthreads();                              // init barrier (full drain, once)

#pragma unroll 1
    for (int t4 = 0; t4 < SEQ / 4; ++t4) {
        if (t4 < SEQ / 4 - 1) {
#pragma unroll
            for (int r = 0; r < 2; ++r)
                tokn[r] = *(const int4*)(tokens + (size_t)(row0 + q * 2 + r) * SEQ + (t4 + 1) * 4);
        }
#pragma unroll
        for (int s = 0; s < 4; ++s) {
            const int p = s & 1;                  // == t&1 (t4*4 is even)
            // ---- MFMA1(t): z1 = e1(t) (in C) + h1(t-1) @ U1 — all registers ----
            f32x4 acc[4];
#pragma unroll
            for (int g = 0; g < 4; ++g) {         // regs 2,3 undefined (dead rows)
                acc[g][0] = e1buf[p][0][g];
                acc[g][1] = e1buf[p][1][g];
            }
#pragma unroll
            for (int g = 0; g < 4; ++g) acc[g] = mfma16(a1f0, b1f[g][0], acc[g]);
#pragma unroll
            for (int g = 0; g < 4; ++g) acc[g] = mfma16(a1f1, b1f[g][1], acc[g]);

            // ---- MFMA2(t-1): z2 = b2 (in C) + [h1(t-1) | h2(t-2)] @ [W2;U2] ----
            // (at t=0 this computes garbage that epi2 discards — frags are zero)
            f32x4 acc2[4];
#pragma unroll
            for (int g = 0; g < 4; ++g) {
                acc2[g][0] = b2v[g];
                acc2[g][1] = b2v[g];
            }
#pragma unroll
            for (int g = 0; g < 4; ++g) acc2[g] = mfma16(a1f0, b2f[g][0], acc2[g]);
#pragma unroll
            for (int g = 0; g < 4; ++g) acc2[g] = mfma16(a1f1, b2f[g][1], acc2[g]);
#pragma unroll
            for (int g = 0; g < 4; ++g) acc2[g] = mfma16(a2f0, b2f[g][2], acc2[g]);
#pragma unroll
            for (int g = 0; g < 4; ++g) acc2[g] = mfma16(a2f1, b2f[g][3], acc2[g]);

            // ---- epi1(t): h1(t) -> buf[p].h1 ----
#pragma unroll
            for (int r = 0; r < 2; ++r) {
                float ig = sigm_e(acc[0][r]);
                float fg = sigm_e(acc[1][r]);
                float gv = tanh_e(acc[2][r]);
                float og = sigm_e(acc[3][r]);
                c1[r] = fg * c1[r] + ig * gv;
                float h1 = og * tanh_e(c1[r]);
                Abuf[p * 2048 + ((u >> 3) * 16 + 4 * q + r) * 8 + (u & 7)] = (f16)h1;
            }

            // ---- epi2(t-1): h2(t-1) -> buf[p].h2 — SKIP at t==0 (h2(-1)=0) ----
            if (t4 | s) {
#pragma unroll
                for (int r = 0; r < 2; ++r) {
                    float ig = sigm_e(acc2[0][r]);
                    float fg = sigm_e(acc2[1][r]);
                    float gv = tanh_e(acc2[2][r]);
                    float og = sigm_e(acc2[3][r]);
                    c2[r] = fg * c2[r] + ig * gv;
                    h2v[r] = og * tanh_e(c2[r]);
                    Abuf[p * 2048 + 1024 + ((u >> 3) * 16 + 4 * q + r) * 8 + (u & 7)] = (f16)h2v[r];
                }
            }

            // gather e1 for t+2 (registers only — pre-barrier, max in-flight)
            if (t4 * 4 + s + 2 < SEQ) {
#pragma unroll
                for (int r = 0; r < 2; ++r) {
                    int tk = (s == 0) ? tokc[r].z : (s == 1) ? tokc[r].w
                           : (s == 2) ? tokn[r].x : tokn[r].y;
                    e1buf[p][r] = E1f4[(size_t)tk * 64 + u];
                }
            }

            barrier_lds();                        // end-of-step; lgkm-only

            // ds_read next epoch's frags: h1(t), h2(t-1) — consumed NEXT iteration
            a1f0 = AbufU[p * 256 + lane];
            a1f1 = AbufU[p * 256 + 64 + lane];
            a2f0 = AbufU[p * 256 + 128 + lane];
            a2f1 = AbufU[p * 256 + 192 + lane];
        }
#pragma unroll
        for (int r = 0; r < 2; ++r) tokc[r] = tokn[r];
    }

    // ---- tail: MFMA2(79) + epi2(79) (registers only, no LDS write needed) ----
    {
        f32x4 acc2[4];
#pragma unroll
        for (int g = 0; g < 4; ++g) {
            acc2[g][0] = b2v[g];
            acc2[g][1] = b2v[g];
        }
#pragma unroll
        for (int g = 0; g < 4; ++g) acc2[g] = mfma16(a1f0, b2f[g][0], acc2[g]);
#pragma unroll
        for (int g = 0; g < 4; ++g) acc2[g] = mfma16(a1f1, b2f[g][1], acc2[g]);
#pragma unroll
        for (int g = 0; g < 4; ++g) acc2[g] = mfma16(a2f0, b2f[g][2], acc2[g]);
#pragma unroll
        for (int g = 0; g < 4; ++g) acc2[g] = mfma16(a2f1, b2f[g][3], acc2[g]);
#pragma unroll
        for (int r = 0; r < 2; ++r) {
            float ig = sigm_e(acc2[0][r]);
            float fg = sigm_e(acc2[1][r]);
            float gv = tanh_e(acc2[2][r]);
            float og = sigm_e(acc2[3][r]);
            c2[r] = fg * c2[r] + ig * gv;
            h2v[r] = og * tanh_e(c2[r]);
        }
    }

    // ---- head: out[row] = sigmoid(sum_u h2[row][u]*Wd[u] + bd) ----
#pragma unroll
    for (int r = 0; r < 2; ++r) {
        float pv = h2v[r] * wdv;
        pv += __shfl_xor(pv, 1, 64);
        pv += __shfl_xor(pv, 2, 64);
        pv += __shfl_xor(pv, 4, 64);
        pv += __shfl_xor(pv, 8, 64);
        if (li == 0) red[w * 8 + q * 2 + r] = pv;
    }
    __syncthreads();
    if (tid < 8) {
        float sum = red[tid] + red[8 + tid] + red[16 + tid] + red[24 + tid] + bdv;
        out[row0 + tid] = sigm_exact(sum);
    }
}

// ---------------- fallback (no workspace): round-1 monolithic ----------------
__device__ __forceinline__ float lane_bcast(float v, int j) {
    return __builtin_bit_cast(float, __builtin_amdgcn_readlane(__builtin_bit_cast(int, v), j));
}
__device__ __forceinline__ float sigm_f(float x)  { return 1.0f / (1.0f + __expf(-x)); }
__device__ __forceinline__ float tanh_f(float x)  { return 2.0f / (1.0f + __expf(-2.0f * x)) - 1.0f; }

__global__ __launch_bounds__(512) void lstm_fused_fallback(
    const int* __restrict__ tokens, const float* __restrict__ emb,
    const float* __restrict__ W1, const float* __restrict__ U1, const float* __restrict__ b1,
    const float* __restrict__ W2, const float* __restrict__ U2, const float* __restrict__ b2,
    const float* __restrict__ Wd, const float* __restrict__ bd, float* __restrict__ out) {
    const int lane = threadIdx.x & 63;
    const int wave = threadIdx.x >> 6;
    const int row0 = blockIdx.x * 16 + wave * 2;
    float bias1[4], bias2[4];
#pragma unroll
    for (int g = 0; g < 4; ++g) { bias1[g] = b1[g * 64 + lane]; bias2[g] = b2[g * 64 + lane]; }
    const float wd = Wd[lane]; const float bdv = bd[0];
    float h1[2] = {0.f, 0.f}, c1[2] = {0.f, 0.f}, h2[2] = {0.f, 0.f}, c2[2] = {0.f, 0.f};
#pragma unroll 1
    for (int t = 0; t < SEQ; ++t) {
        float acc[4][2];
#pragma unroll
        for (int g = 0; g < 4; ++g) { acc[g][0] = bias1[g]; acc[g][1] = bias1[g]; }
        int tokA = __builtin_amdgcn_readfirstlane(tokens[(row0 + 0) * SEQ + t]);
        int tokB = __builtin_amdgcn_readfirstlane(tokens[(row0 + 1) * SEQ + t]);
        const float4* xA = (const float4*)(emb + (size_t)tokA * EMB);
        const float4* xB = (const float4*)(emb + (size_t)tokB * EMB);
#pragma unroll 5
        for (int d4 = 0; d4 < EMB / 4; ++d4) {
            float4 a4 = xA[d4]; float4 b4 = xB[d4];
            float av[4] = {a4.x, a4.y, a4.z, a4.w}; float bv[4] = {b4.x, b4.y, b4.z, b4.w};
#pragma unroll
            for (int e = 0; e < 4; ++e) {
                const float* wrow = W1 + (d4 * 4 + e) * 256;
#pragma unroll
                for (int g = 0; g < 4; ++g) {
                    float wv = wrow[g * 64 + lane];
                    acc[g][0] += av[e] * wv; acc[g][1] += bv[e] * wv;
                }
            }
        }
#pragma unroll 4
        for (int j = 0; j < 64; ++j) {
            float ha = lane_bcast(h1[0], j), hb = lane_bcast(h1[1], j);
            const float* urow = U1 + j * 256;
#pragma unroll
            for (int g = 0; g < 4; ++g) {
                float wv = urow[g * 64 + lane];
                acc[g][0] += ha * wv; acc[g][1] += hb * wv;
            }
        }
#pragma unroll
        for (int r = 0; r < 2; ++r) {
            float ig = sigm_f(acc[0][r]), fg = sigm_f(acc[1][r]);
            float gg = tanh_f(acc[2][r]), og = sigm_f(acc[3][r]);
            c1[r] = fg * c1[r] + ig * gg; h1[r] = og * tanh_f(c1[r]);
        }
        float acc2[4][2];
#pragma unroll
        for (int g = 0; g < 4; ++g) { acc2[g][0] = bias2[g]; acc2[g][1] = bias2[g]; }
#pragma unroll 4
        for (int j = 0; j < 64; ++j) {
            float pa = lane_bcast(h1[0], j), pb = lane_bcast(h1[1], j);
            float qa = lane_bcast(h2[0], j), qb = lane_bcast(h2[1], j);
            const float* w2row = W2 + j * 256; const float* u2row = U2 + j * 256;
#pragma unroll
            for (int g = 0; g < 4; ++g) {
                float w2v = w2row[g * 64 + lane], u2v = u2row[g * 64 + lane];
                acc2[g][0] += pa * w2v + qa * u2v;
                acc2[g][1] += pb * w2v + qb * u2v;
            }
        }
#pragma unroll
        for (int r = 0; r < 2; ++r) {
            float ig = sigm_f(acc2[0][r]), fg = sigm_f(acc2[1][r]);
            float gg = tanh_f(acc2[2][r]), og = sigm_f(acc2[3][r]);
            c2[r] = fg * c2[r] + ig * gg; h2[r] = og * tanh_f(c2[r]);
        }
    }
#pragma unroll
    for (int r = 0; r < 2; ++r) {
        float p = h2[r] * wd;
#pragma unroll
        for (int off = 32; off > 0; off >>= 1) p += __shfl_down(p, off, 64);
        if (lane == 0) out[row0 + r] = sigm_f(p + bdv);
    }
}

extern "C" void kernel_launch(void* const* d_in, const int* in_sizes, int n_in,
                              void* d_out, int out_size, void* d_ws, size_t ws_size,
                              hipStream_t stream) {
    const int*   tokens = (const int*)  d_in[0];
    const float* emb    = (const float*)d_in[1];
    const float* W1     = (const float*)d_in[2];
    const float* U1     = (const float*)d_in[3];
    const float* b1     = (const float*)d_in[4];
    const float* W2     = (const float*)d_in[5];
    const float* U2     = (const float*)d_in[6];
    const float* b2     = (const float*)d_in[7];
    const float* Wd     = (const float*)d_in[8];
    const float* bd     = (const float*)d_in[9];
    float* out = (float*)d_out;

    if (ws_size < (size_t)WS_NEEDED) {
        lstm_fused_fallback<<<256, 512, 0, stream>>>(tokens, emb, W1, U1, b1, W2, U2, b2, Wd, bd, out);
        return;
    }

    char*  ws  = (char*)d_ws;
    float* E1f = (float*)(ws + WS_E1F_OFF);
    uint*  B1f = (uint*) (ws + WS_B1F_OFF);
    uint*  B2f = (uint*) (ws + WS_B2F_OFF);

    prep_e1  <<<NB_E1 + 64, 256, 0, stream>>>(emb, W1, U1, b1, W2, U2, E1f, B1f, B2f);
    lstm_mfma<<<NGRID, 256, 0, stream>>>(tokens, (const f32x4*)E1f,
                                         (const uint4*)B1f, (const uint4*)B2f,
                                         b2, Wd, bd, out);
}